// Round 4
// baseline (399.787 us; speedup 1.0000x reference)
//
#include <hip/hip_runtime.h>
#include <stdint.h>

typedef __bf16 bf16x8 __attribute__((ext_vector_type(8)));
typedef float  f32x4  __attribute__((ext_vector_type(4)));
typedef unsigned short u16x8 __attribute__((ext_vector_type(8)));

static constexpr int NODES  = 50000;
static constexpr int EDGES  = 800000;
static constexpr int INDIM  = 512;
static constexpr int HIDDIM = 256;
static constexpr int NB_SCAN = (NODES + 255) / 256;   // 196
static constexpr int AGG_BLOCKS = NODES / 4;          // 12500 (exact)
static constexpr int RED_BLOCKS = 64;

// ---------------- ws layout (bytes) ----------------
static constexpr size_t OFF_PART = 0;            // f32  [12500][256]
static constexpr size_t OFF_HN   = 51200000;     // bf16 [50000][256] pre-scaled h (both layers)
static constexpr size_t OFF_H1P  = 76800000;     // bf16 [50000][256] relu(layer1) output
static constexpr size_t OFF_W1T  = 102400000;    // bf16 [256][512]
static constexpr size_t OFF_W2T  = 102662144;    // bf16 [256][256]
static constexpr size_t OFF_DEG  = 102793216;    // i32 [50000]
static constexpr size_t OFF_FILL = 102993216;    // i32 [50000]
static constexpr size_t OFF_ROWP = 103193216;    // i32 [50001]
static constexpr size_t OFF_CSR  = 103393280;    // i32 [800000]
static constexpr size_t OFF_BSUM = 106593280;    // i32 [196]
static constexpr size_t OFF_BOFF = 106594304;    // i32 [256]
static constexpr size_t OFF_FLAG = 106595328;    // i32 (1 => edge_index is int64)
static constexpr size_t OFF_P2   = 106595840;    // f32 [64][256]
static constexpr size_t OFF_DINV = 106661376;    // f32 [50000]

__device__ __forceinline__ unsigned short f2bf(float f) {
  unsigned u = __builtin_bit_cast(unsigned, f);
  unsigned r = (u + 0x7FFFu + ((u >> 16) & 1u)) >> 16;   // RNE
  return (unsigned short)r;
}
__device__ __forceinline__ float bf2f(unsigned short u) {
  return __builtin_bit_cast(float, ((unsigned)u) << 16);
}

// ---------------- edge dtype detect ----------------
__global__ void detect_kernel(const int* __restrict__ ei, int* __restrict__ flag) {
  int t = threadIdx.x;  // 64 threads
  unsigned long long b = __ballot(ei[2 * t + 1] == 0);
  if (t == 0) *flag = (b == 0xFFFFFFFFFFFFFFFFull) ? 1 : 0;
}

// ---------------- degree histogram ----------------
__global__ __launch_bounds__(256) void hist_kernel(const int* __restrict__ ei,
                                                   const int* __restrict__ flag,
                                                   int* __restrict__ deg) {
  int e = blockIdx.x * 256 + threadIdx.x;        // grid exact: 3125*256 = 800000
  int f = *flag;
  int d = f ? ei[2 * (EDGES + e)] : ei[EDGES + e];
  atomicAdd(&deg[d], 1);
}

// ---------------- scan (3 kernels) + dinv ----------------
__global__ __launch_bounds__(256) void scan1_kernel(const int* __restrict__ deg,
                                                    int* __restrict__ rowptr,
                                                    int* __restrict__ bsum,
                                                    float* __restrict__ dinv) {
  __shared__ int s[256];
  int t = threadIdx.x, i = blockIdx.x * 256 + t;
  int v = (i < NODES) ? deg[i] : 0;
  if (i < NODES) dinv[i] = rsqrtf((float)(v + 1));   // +1 self-loop
  s[t] = v; __syncthreads();
  for (int off = 1; off < 256; off <<= 1) {
    int x = (t >= off) ? s[t - off] : 0;
    __syncthreads(); s[t] += x; __syncthreads();
  }
  if (i < NODES) rowptr[i] = s[t] - v;               // block-local exclusive
  if (t == 255) bsum[blockIdx.x] = s[255];
}
__global__ __launch_bounds__(256) void scan2_kernel(const int* __restrict__ bsum,
                                                    int* __restrict__ boff,
                                                    int* __restrict__ rowptrN) {
  __shared__ int s[256];
  int t = threadIdx.x;
  int v = (t < NB_SCAN) ? bsum[t] : 0;
  s[t] = v; __syncthreads();
  for (int off = 1; off < 256; off <<= 1) {
    int x = (t >= off) ? s[t - off] : 0;
    __syncthreads(); s[t] += x; __syncthreads();
  }
  if (t < NB_SCAN) boff[t] = s[t] - v;
  if (t == 255) *rowptrN = s[255];
}
__global__ __launch_bounds__(256) void scan3_kernel(int* __restrict__ rowptr,
                                                    const int* __restrict__ boff) {
  int i = blockIdx.x * 256 + threadIdx.x;
  if (i < NODES) rowptr[i] += boff[blockIdx.x];
}

// ---------------- CSR fill ----------------
__global__ __launch_bounds__(256) void fill_kernel(const int* __restrict__ ei,
                                                   const int* __restrict__ flag,
                                                   const int* __restrict__ rowptr,
                                                   int* __restrict__ fill,
                                                   int* __restrict__ csr) {
  int e = blockIdx.x * 256 + threadIdx.x;
  int f = *flag;
  int s, d;
  if (f) { s = ei[2 * e]; d = ei[2 * (EDGES + e)]; }
  else   { s = ei[e];     d = ei[EDGES + e]; }
  int p = atomicAdd(&fill[d], 1);
  csr[rowptr[d] + p] = s;
}

// ---------------- weight transpose + bf16 ----------------
__global__ __launch_bounds__(256) void transw_kernel(const float* __restrict__ W1,
                                                     const float* __restrict__ W2,
                                                     unsigned short* __restrict__ W1T,
                                                     unsigned short* __restrict__ W2T) {
  int t = blockIdx.x * 256 + threadIdx.x;           // 768*256 = 196608 exact
  if (t < INDIM * HIDDIM) {
    int n = t >> 9, k = t & 511;                    // W1T[n][k] = W1[k][n]
    W1T[t] = f2bf(W1[k * HIDDIM + n]);
  } else {
    int u = t - INDIM * HIDDIM;
    int n = u >> 8, k = u & 255;
    W2T[u] = f2bf(W2[k * HIDDIM + n]);
  }
}

// ---------------- barrier-free streaming MFMA GEMM ----------------
// No LDS. Wave tile 32x128; block = 4 waves stacked (128 rows); grid (2, 391).
// A frags loaded global->reg (fp32 path converts in-flight); B frags from L2-hot
// BT panel (256KB / 128KB, fully L2-resident). Zero __syncthreads.
template<int K, bool AFP32>
__global__ __launch_bounds__(256) void gemm_stream_kernel(const void* __restrict__ Av,
                                                          const unsigned short* __restrict__ BT,
                                                          const float* __restrict__ dinv,
                                                          unsigned short* __restrict__ Cn) {
  const int tid = threadIdx.x, wave = tid >> 6, lane = tid & 63;
  const int fr = lane & 15, q = lane >> 4, kq = q * 8;
  const int m0 = blockIdx.y * 128 + wave * 32;
  const int n0 = blockIdx.x * 128;

  int r0 = m0 + fr;       if (r0 > NODES - 1) r0 = NODES - 1;
  int r1 = m0 + 16 + fr;  if (r1 > NODES - 1) r1 = NODES - 1;

  const float* a0f = nullptr; const float* a1f = nullptr;
  const unsigned short* a0h = nullptr; const unsigned short* a1h = nullptr;
  if constexpr (AFP32) {
    a0f = (const float*)Av + (size_t)r0 * K + kq;
    a1f = (const float*)Av + (size_t)r1 * K + kq;
  } else {
    a0h = (const unsigned short*)Av + (size_t)r0 * K + kq;
    a1h = (const unsigned short*)Av + (size_t)r1 * K + kq;
  }
  const unsigned short* bp = BT + (size_t)(n0 + fr) * K + kq;   // + nf*16*K per n-frag

  f32x4 acc[2][8] = {};

#pragma unroll
  for (int kt = 0; kt < K / 32; ++kt) {
    const int k0 = kt * 32;
    bf16x8 bf[8];
#pragma unroll
    for (int nf = 0; nf < 8; ++nf)
      bf[nf] = __builtin_bit_cast(bf16x8, *(const u16x8*)(bp + (size_t)nf * 16 * K + k0));
    bf16x8 af[2];
    if constexpr (AFP32) {
      float4 lo0 = *(const float4*)(a0f + k0), hi0 = *(const float4*)(a0f + k0 + 4);
      float4 lo1 = *(const float4*)(a1f + k0), hi1 = *(const float4*)(a1f + k0 + 4);
      u16x8 c0 = {f2bf(lo0.x), f2bf(lo0.y), f2bf(lo0.z), f2bf(lo0.w),
                  f2bf(hi0.x), f2bf(hi0.y), f2bf(hi0.z), f2bf(hi0.w)};
      u16x8 c1 = {f2bf(lo1.x), f2bf(lo1.y), f2bf(lo1.z), f2bf(lo1.w),
                  f2bf(hi1.x), f2bf(hi1.y), f2bf(hi1.z), f2bf(hi1.w)};
      af[0] = __builtin_bit_cast(bf16x8, c0);
      af[1] = __builtin_bit_cast(bf16x8, c1);
    } else {
      af[0] = __builtin_bit_cast(bf16x8, *(const u16x8*)(a0h + k0));
      af[1] = __builtin_bit_cast(bf16x8, *(const u16x8*)(a1h + k0));
    }
#pragma unroll
    for (int mf = 0; mf < 2; ++mf)
#pragma unroll
      for (int nf = 0; nf < 8; ++nf)
        acc[mf][nf] = __builtin_amdgcn_mfma_f32_16x16x32_bf16(af[mf], bf[nf], acc[mf][nf], 0, 0, 0);
  }

  // epilogue: C/D layout col=lane&15, row=q*4+reg  [m89-verified]
  const int rq = q * 4;
#pragma unroll
  for (int mf = 0; mf < 2; ++mf) {
#pragma unroll
    for (int r = 0; r < 4; ++r) {
      int grow = m0 + mf * 16 + rq + r;
      if (grow < NODES) {
        float dv = dinv[grow];
#pragma unroll
        for (int nf = 0; nf < 8; ++nf) {
          int gcol = n0 + nf * 16 + fr;
          Cn[(size_t)grow * 256 + gcol] = f2bf(acc[mf][nf][r] * dv);
        }
      }
    }
  }
}

// ---------------- gather core: unroll-4 edge loop, 4 rows in flight ----------------
__device__ __forceinline__ float4 gather_node(const unsigned short* __restrict__ hn,
                                              const int* __restrict__ rowptr,
                                              const int* __restrict__ csr,
                                              int node, int c0) {
  ushort4 h = *(const ushort4*)(hn + (size_t)node * 256 + c0);   // self-loop term
  float a0 = bf2f(h.x), a1 = bf2f(h.y), a2 = bf2f(h.z), a3 = bf2f(h.w);
  float b0 = 0.f, b1 = 0.f, b2 = 0.f, b3 = 0.f;
  int e0 = rowptr[node], e1 = rowptr[node + 1];
  int e = e0;
  for (; e + 4 <= e1; e += 4) {
    int s0 = csr[e], s1 = csr[e + 1], s2 = csr[e + 2], s3 = csr[e + 3];
    ushort4 v0 = *(const ushort4*)(hn + (size_t)s0 * 256 + c0);
    ushort4 v1 = *(const ushort4*)(hn + (size_t)s1 * 256 + c0);
    ushort4 v2 = *(const ushort4*)(hn + (size_t)s2 * 256 + c0);
    ushort4 v3 = *(const ushort4*)(hn + (size_t)s3 * 256 + c0);
    a0 += bf2f(v0.x) + bf2f(v1.x);  b0 += bf2f(v2.x) + bf2f(v3.x);
    a1 += bf2f(v0.y) + bf2f(v1.y);  b1 += bf2f(v2.y) + bf2f(v3.y);
    a2 += bf2f(v0.z) + bf2f(v1.z);  b2 += bf2f(v2.z) + bf2f(v3.z);
    a3 += bf2f(v0.w) + bf2f(v1.w);  b3 += bf2f(v2.w) + bf2f(v3.w);
  }
  for (; e < e1; ++e) {
    int s = csr[e];
    ushort4 v = *(const ushort4*)(hn + (size_t)s * 256 + c0);
    a0 += bf2f(v.x); a1 += bf2f(v.y); a2 += bf2f(v.z); a3 += bf2f(v.w);
  }
  return float4{a0 + b0, a1 + b1, a2 + b2, a3 + b3};
}

// ---------------- aggregation: wave per node, CSR gather ----------------
__global__ __launch_bounds__(256) void agg1_kernel(const unsigned short* __restrict__ hn,
                                                   const float* __restrict__ dinv,
                                                   const int* __restrict__ rowptr,
                                                   const int* __restrict__ csr,
                                                   const float* __restrict__ bias,
                                                   unsigned short* __restrict__ outp) {
  int wave = threadIdx.x >> 6, lane = threadIdx.x & 63;
  int node = blockIdx.x * 4 + wave;
  int c0 = lane * 4;
  float4 a = gather_node(hn, rowptr, csr, node, c0);
  float di = dinv[node];
  float4 b = *(const float4*)(bias + c0);
  ushort4 o{f2bf(fmaxf(fmaf(di, a.x, b.x), 0.f)),
            f2bf(fmaxf(fmaf(di, a.y, b.y), 0.f)),
            f2bf(fmaxf(fmaf(di, a.z, b.z), 0.f)),
            f2bf(fmaxf(fmaf(di, a.w, b.w), 0.f))};
  *(ushort4*)(outp + (size_t)node * 256 + c0) = o;
}

__global__ __launch_bounds__(256) void agg2_kernel(const unsigned short* __restrict__ hn,
                                                   const float* __restrict__ dinv,
                                                   const int* __restrict__ rowptr,
                                                   const int* __restrict__ csr,
                                                   const float* __restrict__ bias,
                                                   float* __restrict__ partials) {
  __shared__ float sm[1024];
  int wave = threadIdx.x >> 6, lane = threadIdx.x & 63;
  int node = blockIdx.x * 4 + wave;                 // 12500*4 = 50000 exact
  int c0 = lane * 4;
  float4 a = gather_node(hn, rowptr, csr, node, c0);
  float di = dinv[node];
  float4 b = *(const float4*)(bias + c0);
  sm[wave * 256 + c0 + 0] = fmaxf(fmaf(di, a.x, b.x), 0.f);
  sm[wave * 256 + c0 + 1] = fmaxf(fmaf(di, a.y, b.y), 0.f);
  sm[wave * 256 + c0 + 2] = fmaxf(fmaf(di, a.z, b.z), 0.f);
  sm[wave * 256 + c0 + 3] = fmaxf(fmaf(di, a.w, b.w), 0.f);
  __syncthreads();
  int t = threadIdx.x;
  partials[(size_t)blockIdx.x * 256 + t] = sm[t] + sm[256 + t] + sm[512 + t] + sm[768 + t];
}

// ---------------- readout ----------------
__global__ __launch_bounds__(256) void reduce2_kernel(const float* __restrict__ partials,
                                                      float* __restrict__ p2) {
  int t = threadIdx.x, b = blockIdx.x;              // 64 blocks
  float s = 0.f;
  for (int r = b; r < AGG_BLOCKS; r += RED_BLOCKS) s += partials[(size_t)r * 256 + t];
  p2[b * 256 + t] = s;
}
__global__ __launch_bounds__(256) void final_kernel(const float* __restrict__ p2,
                                                    const float* __restrict__ Wfc,
                                                    const float* __restrict__ bfc,
                                                    float* __restrict__ out) {
  __shared__ float red[256];
  int t = threadIdx.x;
  float s = 0.f;
  for (int b = 0; b < RED_BLOCKS; ++b) s += p2[b * 256 + t];
  float g = s * (1.0f / (float)NODES);
  red[t] = g * Wfc[t];
  __syncthreads();
  for (int off = 128; off > 0; off >>= 1) {
    if (t < off) red[t] += red[t + off];
    __syncthreads();
  }
  if (t == 0) {
    float z = red[0] + bfc[0];
    out[0] = 1.0f / (1.0f + expf(-z));
  }
}

// ---------------- launch ----------------
extern "C" void kernel_launch(void* const* d_in, const int* in_sizes, int n_in,
                              void* d_out, int out_size, void* d_ws, size_t ws_size,
                              hipStream_t stream) {
  (void)in_sizes; (void)n_in; (void)out_size; (void)ws_size;
  const float* x   = (const float*)d_in[0];
  const int*   ei  = (const int*)d_in[1];
  const float* W1  = (const float*)d_in[2];
  const float* b1  = (const float*)d_in[3];
  const float* W2  = (const float*)d_in[4];
  const float* b2  = (const float*)d_in[5];
  const float* Wfc = (const float*)d_in[6];
  const float* bfc = (const float*)d_in[7];
  float* out = (float*)d_out;
  char* ws = (char*)d_ws;

  unsigned short* hn   = (unsigned short*)(ws + OFF_HN);
  unsigned short* h1p  = (unsigned short*)(ws + OFF_H1P);
  unsigned short* w1t  = (unsigned short*)(ws + OFF_W1T);
  unsigned short* w2t  = (unsigned short*)(ws + OFF_W2T);
  int*   deg    = (int*)(ws + OFF_DEG);
  int*   fill   = (int*)(ws + OFF_FILL);
  int*   rowptr = (int*)(ws + OFF_ROWP);
  int*   csr    = (int*)(ws + OFF_CSR);
  int*   bsum   = (int*)(ws + OFF_BSUM);
  int*   boff   = (int*)(ws + OFF_BOFF);
  int*   flag   = (int*)(ws + OFF_FLAG);
  float* part   = (float*)(ws + OFF_PART);
  float* p2     = (float*)(ws + OFF_P2);
  float* dinv   = (float*)(ws + OFF_DINV);

  hipMemsetAsync(ws + OFF_DEG, 0, 400000, stream);  // deg + fill
  detect_kernel<<<1, 64, 0, stream>>>(ei, flag);
  hist_kernel<<<EDGES / 256, 256, 0, stream>>>(ei, flag, deg);
  scan1_kernel<<<NB_SCAN, 256, 0, stream>>>(deg, rowptr, bsum, dinv);
  scan2_kernel<<<1, 256, 0, stream>>>(bsum, boff, rowptr + NODES);
  scan3_kernel<<<NB_SCAN, 256, 0, stream>>>(rowptr, boff);
  fill_kernel<<<EDGES / 256, 256, 0, stream>>>(ei, flag, rowptr, fill, csr);

  transw_kernel<<<(INDIM * HIDDIM + HIDDIM * HIDDIM) / 256, 256, 0, stream>>>(W1, W2, w1t, w2t);

  dim3 ggrid(2, (NODES + 127) / 128);               // (2, 391)
  gemm_stream_kernel<INDIM, true><<<ggrid, 256, 0, stream>>>(x, w1t, dinv, hn);
  agg1_kernel<<<AGG_BLOCKS, 256, 0, stream>>>(hn, dinv, rowptr, csr, b1, h1p);
  gemm_stream_kernel<HIDDIM, false><<<ggrid, 256, 0, stream>>>(h1p, w2t, dinv, hn);
  agg2_kernel<<<AGG_BLOCKS, 256, 0, stream>>>(hn, dinv, rowptr, csr, b2, part);
  reduce2_kernel<<<RED_BLOCKS, 256, 0, stream>>>(part, p2);
  final_kernel<<<1, 256, 0, stream>>>(p2, Wfc, bfc, out);
}

// Round 5
// 318.772 us; speedup vs baseline: 1.2541x; 1.2541x over previous
//
#include <hip/hip_runtime.h>
#include <stdint.h>

typedef __bf16 bf16x8 __attribute__((ext_vector_type(8)));
typedef float  f32x4  __attribute__((ext_vector_type(4)));
typedef unsigned short u16x8 __attribute__((ext_vector_type(8)));

static constexpr int NODES  = 50000;
static constexpr int EDGES  = 800000;
static constexpr int INDIM  = 512;
static constexpr int HIDDIM = 256;
static constexpr int NB_SCAN = (NODES + 255) / 256;   // 196
static constexpr int AGG_BLOCKS = NODES / 4;          // 12500 (exact)
static constexpr int RED_BLOCKS = 64;

// ---------------- ws layout (bytes) ----------------
static constexpr size_t OFF_PART = 0;            // f32  [12500][256]
static constexpr size_t OFF_HN   = 51200000;     // fp8  [50000][256] pre-scaled h (both layers)
static constexpr size_t OFF_H1P  = 76800000;     // bf16 [50000][256] relu(layer1) output
static constexpr size_t OFF_W1T  = 102400000;    // bf16 [256][512]
static constexpr size_t OFF_W2T  = 102662144;    // bf16 [256][256]
static constexpr size_t OFF_DEG  = 102793216;    // i32 [50000]
static constexpr size_t OFF_FILL = 102993216;    // i32 [50000]
static constexpr size_t OFF_ROWP = 103193216;    // i32 [50001]
static constexpr size_t OFF_CSR  = 103393280;    // i32 [800000]
static constexpr size_t OFF_BSUM = 106593280;    // i32 [196]
static constexpr size_t OFF_BOFF = 106594304;    // i32 [256]
static constexpr size_t OFF_FLAG = 106595328;    // i32 (1 => edge_index is int64)
static constexpr size_t OFF_P2   = 106595840;    // f32 [64][256]
static constexpr size_t OFF_DINV = 106661376;    // f32 [50000]

__device__ __forceinline__ unsigned short f2bf(float f) {
  unsigned u = __builtin_bit_cast(unsigned, f);
  unsigned r = (u + 0x7FFFu + ((u >> 16) & 1u)) >> 16;   // RNE
  return (unsigned short)r;
}
__device__ __forceinline__ float bf2f(unsigned short u) {
  return __builtin_bit_cast(float, ((unsigned)u) << 16);
}
__device__ __forceinline__ unsigned char f2fp8(float f) {
  int p = __builtin_amdgcn_cvt_pk_fp8_f32(f, f, 0, false);   // OCP e4m3fn on gfx950
  return (unsigned char)(p & 0xff);
}
__device__ __forceinline__ void acc_fp8(float4& a, unsigned u) {
  a.x += __builtin_amdgcn_cvt_f32_fp8(u, 0);
  a.y += __builtin_amdgcn_cvt_f32_fp8(u, 1);
  a.z += __builtin_amdgcn_cvt_f32_fp8(u, 2);
  a.w += __builtin_amdgcn_cvt_f32_fp8(u, 3);
}

// ---------------- edge dtype detect ----------------
__global__ void detect_kernel(const int* __restrict__ ei, int* __restrict__ flag) {
  int t = threadIdx.x;  // 64 threads
  unsigned long long b = __ballot(ei[2 * t + 1] == 0);
  if (t == 0) *flag = (b == 0xFFFFFFFFFFFFFFFFull) ? 1 : 0;
}

// ---------------- degree histogram ----------------
__global__ __launch_bounds__(256) void hist_kernel(const int* __restrict__ ei,
                                                   const int* __restrict__ flag,
                                                   int* __restrict__ deg) {
  int e = blockIdx.x * 256 + threadIdx.x;        // grid exact: 3125*256 = 800000
  int f = *flag;
  int d = f ? ei[2 * (EDGES + e)] : ei[EDGES + e];
  atomicAdd(&deg[d], 1);
}

// ---------------- scan (3 kernels) + dinv ----------------
__global__ __launch_bounds__(256) void scan1_kernel(const int* __restrict__ deg,
                                                    int* __restrict__ rowptr,
                                                    int* __restrict__ bsum,
                                                    float* __restrict__ dinv) {
  __shared__ int s[256];
  int t = threadIdx.x, i = blockIdx.x * 256 + t;
  int v = (i < NODES) ? deg[i] : 0;
  if (i < NODES) dinv[i] = rsqrtf((float)(v + 1));   // +1 self-loop
  s[t] = v; __syncthreads();
  for (int off = 1; off < 256; off <<= 1) {
    int x = (t >= off) ? s[t - off] : 0;
    __syncthreads(); s[t] += x; __syncthreads();
  }
  if (i < NODES) rowptr[i] = s[t] - v;               // block-local exclusive
  if (t == 255) bsum[blockIdx.x] = s[255];
}
__global__ __launch_bounds__(256) void scan2_kernel(const int* __restrict__ bsum,
                                                    int* __restrict__ boff,
                                                    int* __restrict__ rowptrN) {
  __shared__ int s[256];
  int t = threadIdx.x;
  int v = (t < NB_SCAN) ? bsum[t] : 0;
  s[t] = v; __syncthreads();
  for (int off = 1; off < 256; off <<= 1) {
    int x = (t >= off) ? s[t - off] : 0;
    __syncthreads(); s[t] += x; __syncthreads();
  }
  if (t < NB_SCAN) boff[t] = s[t] - v;
  if (t == 255) *rowptrN = s[255];
}
__global__ __launch_bounds__(256) void scan3_kernel(int* __restrict__ rowptr,
                                                    const int* __restrict__ boff) {
  int i = blockIdx.x * 256 + threadIdx.x;
  if (i < NODES) rowptr[i] += boff[blockIdx.x];
}

// ---------------- CSR fill ----------------
__global__ __launch_bounds__(256) void fill_kernel(const int* __restrict__ ei,
                                                   const int* __restrict__ flag,
                                                   const int* __restrict__ rowptr,
                                                   int* __restrict__ fill,
                                                   int* __restrict__ csr) {
  int e = blockIdx.x * 256 + threadIdx.x;
  int f = *flag;
  int s, d;
  if (f) { s = ei[2 * e]; d = ei[2 * (EDGES + e)]; }
  else   { s = ei[e];     d = ei[EDGES + e]; }
  int p = atomicAdd(&fill[d], 1);
  csr[rowptr[d] + p] = s;
}

// ---------------- weight transpose + bf16 ----------------
__global__ __launch_bounds__(256) void transw_kernel(const float* __restrict__ W1,
                                                     const float* __restrict__ W2,
                                                     unsigned short* __restrict__ W1T,
                                                     unsigned short* __restrict__ W2T) {
  int t = blockIdx.x * 256 + threadIdx.x;           // 768*256 = 196608 exact
  if (t < INDIM * HIDDIM) {
    int n = t >> 9, k = t & 511;                    // W1T[n][k] = W1[k][n]
    W1T[t] = f2bf(W1[k * HIDDIM + n]);
  } else {
    int u = t - INDIM * HIDDIM;
    int n = u >> 8, k = u & 255;
    W2T[u] = f2bf(W2[k * HIDDIM + n]);
  }
}

// ---------------- GEMM: whole-B-panel in LDS (staged once), barrier-free K-loop ----
// BN x K panel of BT staged swizzled (XOR of 16B-group index with row&7 -> 2-way
// bank conflicts = free). 4 waves stacked: block rows = 128, wave tile 32 x BN.
// A loaded global->reg per fragment (independent loads, no barriers => compiler
// pipelines across K). Output written fp8 e4m3 (consumed only by gathers).
template<int K, int BN, bool AFP32>
__global__ __launch_bounds__(256) void gemm_bstage_kernel(const void* __restrict__ Av,
                                                          const unsigned short* __restrict__ BT,
                                                          const float* __restrict__ dinv,
                                                          unsigned char* __restrict__ Cn8) {
  constexpr int GX = HIDDIM / BN;                  // column blocks
  constexpr int NF = BN / 16;                      // n-frags per wave
  constexpr int GPR = K / 8;                       // 16B groups per B row
  __shared__ unsigned short Bs[BN * K];            // 64 KB

  // --- bijective chunked XCD swizzle (m204): same-row blocks share an XCD ---
  const int nwg = gridDim.x;
  const int xcd = blockIdx.x & 7, idx = blockIdx.x >> 3;
  const int qn = nwg >> 3, rn = nwg & 7;
  const int wg = (xcd < rn) ? xcd * (qn + 1) + idx : rn * (qn + 1) + (xcd - rn) * qn + idx;
  const int bm = wg / GX, bn = wg % GX;
  const int m0 = bm * 128, n0 = bn * BN;

  const int tid = threadIdx.x, wave = tid >> 6, lane = tid & 63;
  const int fr = lane & 15, q = lane >> 4;

  // --- stage B panel once (reg -> swizzled ds_write_b128) ---
  {
    constexpr int RPT = (BN * GPR) / 256;          // 16 groups per thread (both configs)
    constexpr int TPR = 256 / BN;                  // threads per row
    const int r = tid / TPR;
    const int gb = (tid % TPR) * RPT;
    const unsigned short* src = BT + (size_t)(n0 + r) * K;
    const int sw = (r & 7) * 8;
#pragma unroll
    for (int j = 0; j < RPT; ++j) {
      int g = gb + j;
      u16x8 v = *(const u16x8*)(src + g * 8);
      *(u16x8*)&Bs[r * K + ((g * 8) ^ sw)] = v;
    }
  }
  __syncthreads();                                  // the only barrier

  const int mrow = m0 + wave * 32;
  int r0 = mrow + fr;      if (r0 > NODES - 1) r0 = NODES - 1;
  int r1 = mrow + 16 + fr; if (r1 > NODES - 1) r1 = NODES - 1;
  const float* a0f = nullptr; const float* a1f = nullptr;
  const unsigned short* a0h = nullptr; const unsigned short* a1h = nullptr;
  if constexpr (AFP32) {
    a0f = (const float*)Av + (size_t)r0 * K + q * 8;
    a1f = (const float*)Av + (size_t)r1 * K + q * 8;
  } else {
    a0h = (const unsigned short*)Av + (size_t)r0 * K + q * 8;
    a1h = (const unsigned short*)Av + (size_t)r1 * K + q * 8;
  }
  const int swr = (fr & 7) * 8;

  f32x4 acc[2][NF] = {};

#pragma unroll
  for (int kt = 0; kt < K / 32; ++kt) {
    const int k0 = kt * 32;
    bf16x8 af[2];
    if constexpr (AFP32) {
      float4 lo0 = *(const float4*)(a0f + k0), hi0 = *(const float4*)(a0f + k0 + 4);
      float4 lo1 = *(const float4*)(a1f + k0), hi1 = *(const float4*)(a1f + k0 + 4);
      u16x8 c0 = {f2bf(lo0.x), f2bf(lo0.y), f2bf(lo0.z), f2bf(lo0.w),
                  f2bf(hi0.x), f2bf(hi0.y), f2bf(hi0.z), f2bf(hi0.w)};
      u16x8 c1 = {f2bf(lo1.x), f2bf(lo1.y), f2bf(lo1.z), f2bf(lo1.w),
                  f2bf(hi1.x), f2bf(hi1.y), f2bf(hi1.z), f2bf(hi1.w)};
      af[0] = __builtin_bit_cast(bf16x8, c0);
      af[1] = __builtin_bit_cast(bf16x8, c1);
    } else {
      af[0] = __builtin_bit_cast(bf16x8, *(const u16x8*)(a0h + k0));
      af[1] = __builtin_bit_cast(bf16x8, *(const u16x8*)(a1h + k0));
    }
    bf16x8 bf[NF];
#pragma unroll
    for (int nf = 0; nf < NF; ++nf) {
      int g8 = (kt * 4 + q) * 8;                   // group byte/2 offset
      bf[nf] = *(const bf16x8*)&Bs[(nf * 16 + fr) * K + (g8 ^ swr)];
    }
#pragma unroll
    for (int mf = 0; mf < 2; ++mf)
#pragma unroll
      for (int nf = 0; nf < NF; ++nf)
        acc[mf][nf] = __builtin_amdgcn_mfma_f32_16x16x32_bf16(af[mf], bf[nf], acc[mf][nf], 0, 0, 0);
  }

  // epilogue: C/D layout col=lane&15, row=q*4+reg ; write fp8
  const int rq = q * 4;
#pragma unroll
  for (int mf = 0; mf < 2; ++mf) {
#pragma unroll
    for (int r = 0; r < 4; ++r) {
      int grow = mrow + mf * 16 + rq + r;
      if (grow < NODES) {
        float dv = dinv[grow];
#pragma unroll
        for (int nf = 0; nf < NF; ++nf) {
          int gcol = n0 + nf * 16 + fr;
          Cn8[(size_t)grow * 256 + gcol] = f2fp8(acc[mf][nf][r] * dv);
        }
      }
    }
  }
}

// ---------------- gather core: fp8 rows, unroll-8 (8 rows in flight) ----------------
__device__ __forceinline__ float4 gather_node(const unsigned char* __restrict__ hn8,
                                              const int* __restrict__ rowptr,
                                              const int* __restrict__ csr,
                                              int node, int boff) {
  float4 A{0.f, 0.f, 0.f, 0.f}, B{0.f, 0.f, 0.f, 0.f};
  unsigned us = *(const unsigned*)(hn8 + (size_t)node * 256 + boff);   // self-loop
  acc_fp8(A, us);
  int e0 = rowptr[node], e1 = rowptr[node + 1];
  int e = e0;
  for (; e + 8 <= e1; e += 8) {
    unsigned u0 = *(const unsigned*)(hn8 + (size_t)csr[e + 0] * 256 + boff);
    unsigned u1 = *(const unsigned*)(hn8 + (size_t)csr[e + 1] * 256 + boff);
    unsigned u2 = *(const unsigned*)(hn8 + (size_t)csr[e + 2] * 256 + boff);
    unsigned u3 = *(const unsigned*)(hn8 + (size_t)csr[e + 3] * 256 + boff);
    unsigned u4 = *(const unsigned*)(hn8 + (size_t)csr[e + 4] * 256 + boff);
    unsigned u5 = *(const unsigned*)(hn8 + (size_t)csr[e + 5] * 256 + boff);
    unsigned u6 = *(const unsigned*)(hn8 + (size_t)csr[e + 6] * 256 + boff);
    unsigned u7 = *(const unsigned*)(hn8 + (size_t)csr[e + 7] * 256 + boff);
    acc_fp8(A, u0); acc_fp8(B, u1); acc_fp8(A, u2); acc_fp8(B, u3);
    acc_fp8(A, u4); acc_fp8(B, u5); acc_fp8(A, u6); acc_fp8(B, u7);
  }
  for (; e + 4 <= e1; e += 4) {
    unsigned u0 = *(const unsigned*)(hn8 + (size_t)csr[e + 0] * 256 + boff);
    unsigned u1 = *(const unsigned*)(hn8 + (size_t)csr[e + 1] * 256 + boff);
    unsigned u2 = *(const unsigned*)(hn8 + (size_t)csr[e + 2] * 256 + boff);
    unsigned u3 = *(const unsigned*)(hn8 + (size_t)csr[e + 3] * 256 + boff);
    acc_fp8(A, u0); acc_fp8(B, u1); acc_fp8(A, u2); acc_fp8(B, u3);
  }
  for (; e < e1; ++e) {
    unsigned u = *(const unsigned*)(hn8 + (size_t)csr[e] * 256 + boff);
    acc_fp8(A, u);
  }
  return float4{A.x + B.x, A.y + B.y, A.z + B.z, A.w + B.w};
}

// ---------------- aggregation: wave per node, CSR gather ----------------
__global__ __launch_bounds__(256) void agg1_kernel(const unsigned char* __restrict__ hn8,
                                                   const float* __restrict__ dinv,
                                                   const int* __restrict__ rowptr,
                                                   const int* __restrict__ csr,
                                                   const float* __restrict__ bias,
                                                   unsigned short* __restrict__ outp) {
  int wave = threadIdx.x >> 6, lane = threadIdx.x & 63;
  int node = blockIdx.x * 4 + wave;
  int c0 = lane * 4;
  float4 a = gather_node(hn8, rowptr, csr, node, c0);
  float di = dinv[node];
  float4 b = *(const float4*)(bias + c0);
  ushort4 o{f2bf(fmaxf(fmaf(di, a.x, b.x), 0.f)),
            f2bf(fmaxf(fmaf(di, a.y, b.y), 0.f)),
            f2bf(fmaxf(fmaf(di, a.z, b.z), 0.f)),
            f2bf(fmaxf(fmaf(di, a.w, b.w), 0.f))};
  *(ushort4*)(outp + (size_t)node * 256 + c0) = o;
}

__global__ __launch_bounds__(256) void agg2_kernel(const unsigned char* __restrict__ hn8,
                                                   const float* __restrict__ dinv,
                                                   const int* __restrict__ rowptr,
                                                   const int* __restrict__ csr,
                                                   const float* __restrict__ bias,
                                                   float* __restrict__ partials) {
  __shared__ float sm[1024];
  int wave = threadIdx.x >> 6, lane = threadIdx.x & 63;
  int node = blockIdx.x * 4 + wave;                 // 12500*4 = 50000 exact
  int c0 = lane * 4;
  float4 a = gather_node(hn8, rowptr, csr, node, c0);
  float di = dinv[node];
  float4 b = *(const float4*)(bias + c0);
  sm[wave * 256 + c0 + 0] = fmaxf(fmaf(di, a.x, b.x), 0.f);
  sm[wave * 256 + c0 + 1] = fmaxf(fmaf(di, a.y, b.y), 0.f);
  sm[wave * 256 + c0 + 2] = fmaxf(fmaf(di, a.z, b.z), 0.f);
  sm[wave * 256 + c0 + 3] = fmaxf(fmaf(di, a.w, b.w), 0.f);
  __syncthreads();
  int t = threadIdx.x;
  partials[(size_t)blockIdx.x * 256 + t] = sm[t] + sm[256 + t] + sm[512 + t] + sm[768 + t];
}

// ---------------- readout ----------------
__global__ __launch_bounds__(256) void reduce2_kernel(const float* __restrict__ partials,
                                                      float* __restrict__ p2) {
  int t = threadIdx.x, b = blockIdx.x;              // 64 blocks
  float s = 0.f;
  for (int r = b; r < AGG_BLOCKS; r += RED_BLOCKS) s += partials[(size_t)r * 256 + t];
  p2[b * 256 + t] = s;
}
__global__ __launch_bounds__(256) void final_kernel(const float* __restrict__ p2,
                                                    const float* __restrict__ Wfc,
                                                    const float* __restrict__ bfc,
                                                    float* __restrict__ out) {
  __shared__ float red[256];
  int t = threadIdx.x;
  float s = 0.f;
  for (int b = 0; b < RED_BLOCKS; ++b) s += p2[b * 256 + t];
  float g = s * (1.0f / (float)NODES);
  red[t] = g * Wfc[t];
  __syncthreads();
  for (int off = 128; off > 0; off >>= 1) {
    if (t < off) red[t] += red[t + off];
    __syncthreads();
  }
  if (t == 0) {
    float z = red[0] + bfc[0];
    out[0] = 1.0f / (1.0f + expf(-z));
  }
}

// ---------------- launch ----------------
extern "C" void kernel_launch(void* const* d_in, const int* in_sizes, int n_in,
                              void* d_out, int out_size, void* d_ws, size_t ws_size,
                              hipStream_t stream) {
  (void)in_sizes; (void)n_in; (void)out_size; (void)ws_size;
  const float* x   = (const float*)d_in[0];
  const int*   ei  = (const int*)d_in[1];
  const float* W1  = (const float*)d_in[2];
  const float* b1  = (const float*)d_in[3];
  const float* W2  = (const float*)d_in[4];
  const float* b2  = (const float*)d_in[5];
  const float* Wfc = (const float*)d_in[6];
  const float* bfc = (const float*)d_in[7];
  float* out = (float*)d_out;
  char* ws = (char*)d_ws;

  unsigned char*  hn8  = (unsigned char*)(ws + OFF_HN);
  unsigned short* h1p  = (unsigned short*)(ws + OFF_H1P);
  unsigned short* w1t  = (unsigned short*)(ws + OFF_W1T);
  unsigned short* w2t  = (unsigned short*)(ws + OFF_W2T);
  int*   deg    = (int*)(ws + OFF_DEG);
  int*   fill   = (int*)(ws + OFF_FILL);
  int*   rowptr = (int*)(ws + OFF_ROWP);
  int*   csr    = (int*)(ws + OFF_CSR);
  int*   bsum   = (int*)(ws + OFF_BSUM);
  int*   boff   = (int*)(ws + OFF_BOFF);
  int*   flag   = (int*)(ws + OFF_FLAG);
  float* part   = (float*)(ws + OFF_PART);
  float* p2     = (float*)(ws + OFF_P2);
  float* dinv   = (float*)(ws + OFF_DINV);

  hipMemsetAsync(ws + OFF_DEG, 0, 400000, stream);  // deg + fill
  detect_kernel<<<1, 64, 0, stream>>>(ei, flag);
  hist_kernel<<<EDGES / 256, 256, 0, stream>>>(ei, flag, deg);
  scan1_kernel<<<NB_SCAN, 256, 0, stream>>>(deg, rowptr, bsum, dinv);
  scan2_kernel<<<1, 256, 0, stream>>>(bsum, boff, rowptr + NODES);
  scan3_kernel<<<NB_SCAN, 256, 0, stream>>>(rowptr, boff);
  fill_kernel<<<EDGES / 256, 256, 0, stream>>>(ei, flag, rowptr, fill, csr);

  transw_kernel<<<(INDIM * HIDDIM + HIDDIM * HIDDIM) / 256, 256, 0, stream>>>(W1, W2, w1t, w2t);

  const int MB = (NODES + 127) / 128;               // 391
  // gemm1: BN=64 -> grid 4*391 = 1564 blocks, 64KB LDS, 2 blocks/CU
  gemm_bstage_kernel<INDIM, 64, true><<<4 * MB, 256, 0, stream>>>(x, w1t, dinv, hn8);
  agg1_kernel<<<AGG_BLOCKS, 256, 0, stream>>>(hn8, dinv, rowptr, csr, b1, h1p);
  // gemm2: BN=128 -> grid 2*391 = 782 blocks, 64KB LDS, 2 blocks/CU
  gemm_bstage_kernel<HIDDIM, 128, false><<<2 * MB, 256, 0, stream>>>(h1p, w2t, dinv, hn8);
  agg2_kernel<<<AGG_BLOCKS, 256, 0, stream>>>(hn8, dinv, rowptr, csr, b2, part);
  reduce2_kernel<<<RED_BLOCKS, 256, 0, stream>>>(part, p2);
  final_kernel<<<1, 256, 0, stream>>>(p2, Wfc, bfc, out);
}

// Round 6
// 282.536 us; speedup vs baseline: 1.4150x; 1.1283x over previous
//
#include <hip/hip_runtime.h>
#include <stdint.h>

#define AS1 __attribute__((address_space(1)))
#define AS3 __attribute__((address_space(3)))

typedef __bf16 bf16x8 __attribute__((ext_vector_type(8)));
typedef float  f32x4  __attribute__((ext_vector_type(4)));
typedef unsigned short u16x8 __attribute__((ext_vector_type(8)));

static constexpr int NODES  = 50000;
static constexpr int EDGES  = 800000;
static constexpr int INDIM  = 512;
static constexpr int HIDDIM = 256;
static constexpr int NB_SCAN = (NODES + 255) / 256;   // 196
static constexpr int AGG_BLOCKS = NODES / 4;          // 12500 (exact)
static constexpr int RED_BLOCKS = 64;
static constexpr int GEMM_MB = (NODES + 63) / 64;     // 782 row-blocks (BM=64)

// ---------------- ws layout (bytes) ----------------
static constexpr size_t OFF_PART = 0;            // f32  [12500][256]
static constexpr size_t OFF_HN   = 51200000;     // fp8  [50000][256] pre-scaled h (both layers)
static constexpr size_t OFF_H1P  = 76800000;     // bf16 [50000][256] relu(layer1) output
static constexpr size_t OFF_W1T  = 102400000;    // bf16 [256][512]
static constexpr size_t OFF_W2T  = 102662144;    // bf16 [256][256]
static constexpr size_t OFF_DEG  = 102793216;    // i32 [50000]
static constexpr size_t OFF_FILL = 102993216;    // i32 [50000]
static constexpr size_t OFF_ROWP = 103193216;    // i32 [50001]
static constexpr size_t OFF_CSR  = 103393280;    // i32 [800000]
static constexpr size_t OFF_BSUM = 106593280;    // i32 [196]
static constexpr size_t OFF_BOFF = 106594304;    // i32 [256]
static constexpr size_t OFF_FLAG = 106595328;    // i32 (1 => edge_index is int64)
static constexpr size_t OFF_P2   = 106595840;    // f32 [64][256]
static constexpr size_t OFF_DINV = 106661376;    // f32 [50000]

__device__ __forceinline__ unsigned short f2bf(float f) {
  unsigned u = __builtin_bit_cast(unsigned, f);
  unsigned r = (u + 0x7FFFu + ((u >> 16) & 1u)) >> 16;   // RNE
  return (unsigned short)r;
}
__device__ __forceinline__ float bf2f(unsigned short u) {
  return __builtin_bit_cast(float, ((unsigned)u) << 16);
}
__device__ __forceinline__ unsigned char f2fp8(float f) {
  int p = __builtin_amdgcn_cvt_pk_fp8_f32(f, f, 0, false);   // OCP e4m3fn on gfx950
  return (unsigned char)(p & 0xff);
}
__device__ __forceinline__ void acc_fp8(float4& a, unsigned u) {
  a.x += __builtin_amdgcn_cvt_f32_fp8(u, 0);
  a.y += __builtin_amdgcn_cvt_f32_fp8(u, 1);
  a.z += __builtin_amdgcn_cvt_f32_fp8(u, 2);
  a.w += __builtin_amdgcn_cvt_f32_fp8(u, 3);
}
__device__ __forceinline__ void gload_lds16(const unsigned short* g, unsigned short* l) {
  __builtin_amdgcn_global_load_lds((const AS1 void*)g, (AS3 void*)l, 16, 0, 0);
}

// ---------------- edge dtype detect ----------------
__global__ void detect_kernel(const int* __restrict__ ei, int* __restrict__ flag) {
  int t = threadIdx.x;  // 64 threads
  unsigned long long b = __ballot(ei[2 * t + 1] == 0);
  if (t == 0) *flag = (b == 0xFFFFFFFFFFFFFFFFull) ? 1 : 0;
}

// ---------------- degree histogram ----------------
__global__ __launch_bounds__(256) void hist_kernel(const int* __restrict__ ei,
                                                   const int* __restrict__ flag,
                                                   int* __restrict__ deg) {
  int e = blockIdx.x * 256 + threadIdx.x;        // grid exact: 3125*256 = 800000
  int f = *flag;
  int d = f ? ei[2 * (EDGES + e)] : ei[EDGES + e];
  atomicAdd(&deg[d], 1);
}

// ---------------- scan (3 kernels) + dinv ----------------
__global__ __launch_bounds__(256) void scan1_kernel(const int* __restrict__ deg,
                                                    int* __restrict__ rowptr,
                                                    int* __restrict__ bsum,
                                                    float* __restrict__ dinv) {
  __shared__ int s[256];
  int t = threadIdx.x, i = blockIdx.x * 256 + t;
  int v = (i < NODES) ? deg[i] : 0;
  if (i < NODES) dinv[i] = rsqrtf((float)(v + 1));   // +1 self-loop
  s[t] = v; __syncthreads();
  for (int off = 1; off < 256; off <<= 1) {
    int x = (t >= off) ? s[t - off] : 0;
    __syncthreads(); s[t] += x; __syncthreads();
  }
  if (i < NODES) rowptr[i] = s[t] - v;               // block-local exclusive
  if (t == 255) bsum[blockIdx.x] = s[255];
}
__global__ __launch_bounds__(256) void scan2_kernel(const int* __restrict__ bsum,
                                                    int* __restrict__ boff,
                                                    int* __restrict__ rowptrN) {
  __shared__ int s[256];
  int t = threadIdx.x;
  int v = (t < NB_SCAN) ? bsum[t] : 0;
  s[t] = v; __syncthreads();
  for (int off = 1; off < 256; off <<= 1) {
    int x = (t >= off) ? s[t - off] : 0;
    __syncthreads(); s[t] += x; __syncthreads();
  }
  if (t < NB_SCAN) boff[t] = s[t] - v;
  if (t == 255) *rowptrN = s[255];
}
__global__ __launch_bounds__(256) void scan3_kernel(int* __restrict__ rowptr,
                                                    const int* __restrict__ boff) {
  int i = blockIdx.x * 256 + threadIdx.x;
  if (i < NODES) rowptr[i] += boff[blockIdx.x];
}

// ---------------- CSR fill ----------------
__global__ __launch_bounds__(256) void fill_kernel(const int* __restrict__ ei,
                                                   const int* __restrict__ flag,
                                                   const int* __restrict__ rowptr,
                                                   int* __restrict__ fill,
                                                   int* __restrict__ csr) {
  int e = blockIdx.x * 256 + threadIdx.x;
  int f = *flag;
  int s, d;
  if (f) { s = ei[2 * e]; d = ei[2 * (EDGES + e)]; }
  else   { s = ei[e];     d = ei[EDGES + e]; }
  int p = atomicAdd(&fill[d], 1);
  csr[rowptr[d] + p] = s;
}

// ---------------- weight transpose + bf16 ----------------
__global__ __launch_bounds__(256) void transw_kernel(const float* __restrict__ W1,
                                                     const float* __restrict__ W2,
                                                     unsigned short* __restrict__ W1T,
                                                     unsigned short* __restrict__ W2T) {
  int t = blockIdx.x * 256 + threadIdx.x;           // 768*256 = 196608 exact
  if (t < INDIM * HIDDIM) {
    int n = t >> 9, k = t & 511;                    // W1T[n][k] = W1[k][n]
    W1T[t] = f2bf(W1[k * HIDDIM + n]);
  } else {
    int u = t - INDIM * HIDDIM;
    int n = u >> 8, k = u & 255;
    W2T[u] = f2bf(W2[k * HIDDIM + n]);
  }
}

// ---------------- GEMM: 64x128 tile, BK=64, 2-phase dbuf, XOR-swizzled LDS ----
// XCD-chunked bijective swizzle, n-fastest order: both column-blocks of an A
// row-panel run adjacent on one XCD (A 2nd read = L2 hit); 262KB B panel stays
// L2-resident per XCD. B (and bf16 A) staged via global_load_lds with
// pre-swizzled SOURCE (G21: linear dest + inverse-swz source + swz read).
// fp32 A staged reg->cvt->swizzled ds_write. One barrier per K-step.
template<int K, bool AFP32>
__global__ __launch_bounds__(256) void gemm_kernel(const void* __restrict__ Av,
                                                   const unsigned short* __restrict__ BT,
                                                   const float* __restrict__ dinv,
                                                   unsigned char* __restrict__ Cn8) {
  constexpr int NSTEP = K / 64;
  __shared__ unsigned short As[2][64 * 64];    // 8 KB per buf
  __shared__ unsigned short Bs[2][128 * 64];   // 16 KB per buf
  const int tid = threadIdx.x, wave = tid >> 6, lane = tid & 63;
  const int fr = lane & 15, q = lane >> 4;
  const int wr = wave >> 1, wc = wave & 1;

  // bijective chunked XCD swizzle (m204); wg&1 = column block (n-fastest)
  const int nwg = gridDim.x;
  const int xcd = blockIdx.x & 7, idx = blockIdx.x >> 3;
  const int qn = nwg >> 3, rn = nwg & 7;
  const int wg = (xcd < rn) ? xcd * (qn + 1) + idx
                            : rn * (qn + 1) + (xcd - rn) * qn + idx;
  const int m0 = (wg >> 1) * 64, n0 = (wg & 1) * 128;

  const int srow8 = lane >> 3;                 // row within an 8-row chunk
  const int sg    = (lane & 7) ^ srow8;        // pre-swizzled source group
  const unsigned short* a16 = (const unsigned short*)Av;
  const float*          a32 = (const float*)Av;

  f32x4 acc[2][4] = {};
  float4 fa[2][2];                              // fp32 A staging regs

  // ---- staging helpers (inline) ----
#define STAGE_B(buf, kb)                                                      \
  {                                                                           \
    _Pragma("unroll")                                                         \
    for (int c = 0; c < 4; ++c) {                                             \
      int i = wave * 4 + c;                                                   \
      int gr = n0 + i * 8 + srow8;                                            \
      gload_lds16(BT + (size_t)gr * K + (kb) + sg * 8, &Bs[buf][i * 512]);    \
    }                                                                         \
  }
#define STAGE_A16(buf, kb)                                                    \
  {                                                                           \
    _Pragma("unroll")                                                         \
    for (int c = 0; c < 2; ++c) {                                             \
      int i = wave * 2 + c;                                                   \
      int gr = m0 + i * 8 + srow8; if (gr > NODES - 1) gr = NODES - 1;        \
      gload_lds16(a16 + (size_t)gr * K + (kb) + sg * 8, &As[buf][i * 512]);   \
    }                                                                         \
  }
#define LOAD_A32(kb)                                                          \
  {                                                                           \
    _Pragma("unroll")                                                         \
    for (int j = 0; j < 2; ++j) {                                             \
      int G = tid * 2 + j;                                                    \
      int row = G >> 3, g = G & 7;                                            \
      int gr = m0 + row; if (gr > NODES - 1) gr = NODES - 1;                  \
      const float* p = a32 + (size_t)gr * K + (kb) + g * 8;                   \
      fa[j][0] = *(const float4*)p;                                           \
      fa[j][1] = *(const float4*)(p + 4);                                     \
    }                                                                         \
  }
#define WRITE_A32(buf)                                                        \
  {                                                                           \
    _Pragma("unroll")                                                         \
    for (int j = 0; j < 2; ++j) {                                             \
      int G = tid * 2 + j;                                                    \
      int row = G >> 3, g = G & 7;                                            \
      u16x8 o = {f2bf(fa[j][0].x), f2bf(fa[j][0].y), f2bf(fa[j][0].z),        \
                 f2bf(fa[j][0].w), f2bf(fa[j][1].x), f2bf(fa[j][1].y),        \
                 f2bf(fa[j][1].z), f2bf(fa[j][1].w)};                         \
      *(u16x8*)&As[buf][row * 64 + ((g ^ (row & 7)) * 8)] = o;                \
    }                                                                         \
  }

  // ---- prologue: stage step 0 into buf 0 ----
  if constexpr (AFP32) { LOAD_A32(0); WRITE_A32(0); }
  else                 { STAGE_A16(0, 0); }
  STAGE_B(0, 0);
  __syncthreads();

  for (int t = 0; t < NSTEP; ++t) {
    const int cur = t & 1, nxt = cur ^ 1;
    const int kb1 = (t + 1) * 64;
    if (t + 1 < NSTEP) {                        // issue next-tile loads first
      if constexpr (AFP32) { LOAD_A32(kb1); }
      else                 { STAGE_A16(nxt, kb1); }
      STAGE_B(nxt, kb1);
    }
    // compute current tile: 2 K-subtiles of 32
#pragma unroll
    for (int kk = 0; kk < 2; ++kk) {
      const int so = ((kk * 4 + q) ^ (fr & 7)) * 8;
      bf16x8 af[2], bq[4];
#pragma unroll
      for (int m = 0; m < 2; ++m)
        af[m] = *(const bf16x8*)&As[cur][(wr * 32 + m * 16 + fr) * 64 + so];
#pragma unroll
      for (int n = 0; n < 4; ++n)
        bq[n] = *(const bf16x8*)&Bs[cur][(wc * 64 + n * 16 + fr) * 64 + so];
#pragma unroll
      for (int m = 0; m < 2; ++m)
#pragma unroll
        for (int n = 0; n < 4; ++n)
          acc[m][n] = __builtin_amdgcn_mfma_f32_16x16x32_bf16(af[m], bq[n], acc[m][n], 0, 0, 0);
    }
    if (t + 1 < NSTEP) {
      if constexpr (AFP32) { WRITE_A32(nxt); }  // land A prefetch after MFMAs
    }
    __syncthreads();
  }
#undef STAGE_B
#undef STAGE_A16
#undef LOAD_A32
#undef WRITE_A32

  // epilogue: C/D layout col=lane&15, row=q*4+reg ; write fp8 with dinv scale
  const int rq = q * 4;
#pragma unroll
  for (int m = 0; m < 2; ++m) {
    int rbase = m0 + wr * 32 + m * 16 + rq;
#pragma unroll
    for (int r = 0; r < 4; ++r) {
      int grow = rbase + r;
      if (grow < NODES) {
        float dv = dinv[grow];
#pragma unroll
        for (int n = 0; n < 4; ++n) {
          int gcol = n0 + wc * 64 + n * 16 + fr;
          Cn8[(size_t)grow * 256 + gcol] = f2fp8(acc[m][n][r] * dv);
        }
      }
    }
  }
}

// ---------------- gather core: fp8 rows, unroll-8 (8 rows in flight) ----------------
__device__ __forceinline__ float4 gather_node(const unsigned char* __restrict__ hn8,
                                              const int* __restrict__ rowptr,
                                              const int* __restrict__ csr,
                                              int node, int boff) {
  float4 A{0.f, 0.f, 0.f, 0.f}, B{0.f, 0.f, 0.f, 0.f};
  unsigned us = *(const unsigned*)(hn8 + (size_t)node * 256 + boff);   // self-loop
  acc_fp8(A, us);
  int e0 = rowptr[node], e1 = rowptr[node + 1];
  int e = e0;
  for (; e + 8 <= e1; e += 8) {
    unsigned u0 = *(const unsigned*)(hn8 + (size_t)csr[e + 0] * 256 + boff);
    unsigned u1 = *(const unsigned*)(hn8 + (size_t)csr[e + 1] * 256 + boff);
    unsigned u2 = *(const unsigned*)(hn8 + (size_t)csr[e + 2] * 256 + boff);
    unsigned u3 = *(const unsigned*)(hn8 + (size_t)csr[e + 3] * 256 + boff);
    unsigned u4 = *(const unsigned*)(hn8 + (size_t)csr[e + 4] * 256 + boff);
    unsigned u5 = *(const unsigned*)(hn8 + (size_t)csr[e + 5] * 256 + boff);
    unsigned u6 = *(const unsigned*)(hn8 + (size_t)csr[e + 6] * 256 + boff);
    unsigned u7 = *(const unsigned*)(hn8 + (size_t)csr[e + 7] * 256 + boff);
    acc_fp8(A, u0); acc_fp8(B, u1); acc_fp8(A, u2); acc_fp8(B, u3);
    acc_fp8(A, u4); acc_fp8(B, u5); acc_fp8(A, u6); acc_fp8(B, u7);
  }
  for (; e + 4 <= e1; e += 4) {
    unsigned u0 = *(const unsigned*)(hn8 + (size_t)csr[e + 0] * 256 + boff);
    unsigned u1 = *(const unsigned*)(hn8 + (size_t)csr[e + 1] * 256 + boff);
    unsigned u2 = *(const unsigned*)(hn8 + (size_t)csr[e + 2] * 256 + boff);
    unsigned u3 = *(const unsigned*)(hn8 + (size_t)csr[e + 3] * 256 + boff);
    acc_fp8(A, u0); acc_fp8(B, u1); acc_fp8(A, u2); acc_fp8(B, u3);
  }
  for (; e < e1; ++e) {
    unsigned u = *(const unsigned*)(hn8 + (size_t)csr[e] * 256 + boff);
    acc_fp8(A, u);
  }
  return float4{A.x + B.x, A.y + B.y, A.z + B.z, A.w + B.w};
}

// ---------------- aggregation: wave per node, CSR gather ----------------
__global__ __launch_bounds__(256) void agg1_kernel(const unsigned char* __restrict__ hn8,
                                                   const float* __restrict__ dinv,
                                                   const int* __restrict__ rowptr,
                                                   const int* __restrict__ csr,
                                                   const float* __restrict__ bias,
                                                   unsigned short* __restrict__ outp) {
  int wave = threadIdx.x >> 6, lane = threadIdx.x & 63;
  int node = blockIdx.x * 4 + wave;
  int c0 = lane * 4;
  float4 a = gather_node(hn8, rowptr, csr, node, c0);
  float di = dinv[node];
  float4 b = *(const float4*)(bias + c0);
  ushort4 o{f2bf(fmaxf(fmaf(di, a.x, b.x), 0.f)),
            f2bf(fmaxf(fmaf(di, a.y, b.y), 0.f)),
            f2bf(fmaxf(fmaf(di, a.z, b.z), 0.f)),
            f2bf(fmaxf(fmaf(di, a.w, b.w), 0.f))};
  *(ushort4*)(outp + (size_t)node * 256 + c0) = o;
}

__global__ __launch_bounds__(256) void agg2_kernel(const unsigned char* __restrict__ hn8,
                                                   const float* __restrict__ dinv,
                                                   const int* __restrict__ rowptr,
                                                   const int* __restrict__ csr,
                                                   const float* __restrict__ bias,
                                                   float* __restrict__ partials) {
  __shared__ float sm[1024];
  int wave = threadIdx.x >> 6, lane = threadIdx.x & 63;
  int node = blockIdx.x * 4 + wave;                 // 12500*4 = 50000 exact
  int c0 = lane * 4;
  float4 a = gather_node(hn8, rowptr, csr, node, c0);
  float di = dinv[node];
  float4 b = *(const float4*)(bias + c0);
  sm[wave * 256 + c0 + 0] = fmaxf(fmaf(di, a.x, b.x), 0.f);
  sm[wave * 256 + c0 + 1] = fmaxf(fmaf(di, a.y, b.y), 0.f);
  sm[wave * 256 + c0 + 2] = fmaxf(fmaf(di, a.z, b.z), 0.f);
  sm[wave * 256 + c0 + 3] = fmaxf(fmaf(di, a.w, b.w), 0.f);
  __syncthreads();
  int t = threadIdx.x;
  partials[(size_t)blockIdx.x * 256 + t] = sm[t] + sm[256 + t] + sm[512 + t] + sm[768 + t];
}

// ---------------- readout ----------------
__global__ __launch_bounds__(256) void reduce2_kernel(const float* __restrict__ partials,
                                                      float* __restrict__ p2) {
  int t = threadIdx.x, b = blockIdx.x;              // 64 blocks
  float s = 0.f;
  for (int r = b; r < AGG_BLOCKS; r += RED_BLOCKS) s += partials[(size_t)r * 256 + t];
  p2[b * 256 + t] = s;
}
__global__ __launch_bounds__(256) void final_kernel(const float* __restrict__ p2,
                                                    const float* __restrict__ Wfc,
                                                    const float* __restrict__ bfc,
                                                    float* __restrict__ out) {
  __shared__ float red[256];
  int t = threadIdx.x;
  float s = 0.f;
  for (int b = 0; b < RED_BLOCKS; ++b) s += p2[b * 256 + t];
  float g = s * (1.0f / (float)NODES);
  red[t] = g * Wfc[t];
  __syncthreads();
  for (int off = 128; off > 0; off >>= 1) {
    if (t < off) red[t] += red[t + off];
    __syncthreads();
  }
  if (t == 0) {
    float z = red[0] + bfc[0];
    out[0] = 1.0f / (1.0f + expf(-z));
  }
}

// ---------------- launch ----------------
extern "C" void kernel_launch(void* const* d_in, const int* in_sizes, int n_in,
                              void* d_out, int out_size, void* d_ws, size_t ws_size,
                              hipStream_t stream) {
  (void)in_sizes; (void)n_in; (void)out_size; (void)ws_size;
  const float* x   = (const float*)d_in[0];
  const int*   ei  = (const int*)d_in[1];
  const float* W1  = (const float*)d_in[2];
  const float* b1  = (const float*)d_in[3];
  const float* W2  = (const float*)d_in[4];
  const float* b2  = (const float*)d_in[5];
  const float* Wfc = (const float*)d_in[6];
  const float* bfc = (const float*)d_in[7];
  float* out = (float*)d_out;
  char* ws = (char*)d_ws;

  unsigned char*  hn8  = (unsigned char*)(ws + OFF_HN);
  unsigned short* h1p  = (unsigned short*)(ws + OFF_H1P);
  unsigned short* w1t  = (unsigned short*)(ws + OFF_W1T);
  unsigned short* w2t  = (unsigned short*)(ws + OFF_W2T);
  int*   deg    = (int*)(ws + OFF_DEG);
  int*   fill   = (int*)(ws + OFF_FILL);
  int*   rowptr = (int*)(ws + OFF_ROWP);
  int*   csr    = (int*)(ws + OFF_CSR);
  int*   bsum   = (int*)(ws + OFF_BSUM);
  int*   boff   = (int*)(ws + OFF_BOFF);
  int*   flag   = (int*)(ws + OFF_FLAG);
  float* part   = (float*)(ws + OFF_PART);
  float* p2     = (float*)(ws + OFF_P2);
  float* dinv   = (float*)(ws + OFF_DINV);

  hipMemsetAsync(ws + OFF_DEG, 0, 400000, stream);  // deg + fill
  detect_kernel<<<1, 64, 0, stream>>>(ei, flag);
  hist_kernel<<<EDGES / 256, 256, 0, stream>>>(ei, flag, deg);
  scan1_kernel<<<NB_SCAN, 256, 0, stream>>>(deg, rowptr, bsum, dinv);
  scan2_kernel<<<1, 256, 0, stream>>>(bsum, boff, rowptr + NODES);
  scan3_kernel<<<NB_SCAN, 256, 0, stream>>>(rowptr, boff);
  fill_kernel<<<EDGES / 256, 256, 0, stream>>>(ei, flag, rowptr, fill, csr);

  transw_kernel<<<(INDIM * HIDDIM + HIDDIM * HIDDIM) / 256, 256, 0, stream>>>(W1, W2, w1t, w2t);

  const int GG = 2 * GEMM_MB;                       // 1564 blocks
  gemm_kernel<INDIM, true><<<GG, 256, 0, stream>>>(x, w1t, dinv, hn8);
  agg1_kernel<<<AGG_BLOCKS, 256, 0, stream>>>(hn8, dinv, rowptr, csr, b1, h1p);
  gemm_kernel<HIDDIM, false><<<GG, 256, 0, stream>>>(h1p, w2t, dinv, hn8);
  agg2_kernel<<<AGG_BLOCKS, 256, 0, stream>>>(hn8, dinv, rowptr, csr, b2, part);
  reduce2_kernel<<<RED_BLOCKS, 256, 0, stream>>>(part, p2);
  final_kernel<<<1, 256, 0, stream>>>(p2, Wfc, bfc, out);
}